// Round 7
// baseline (229.883 us; speedup 1.0000x reference)
//
#include <hip/hip_runtime.h>
#include <math.h>

#define NB 16
#define NN 1024
#define NH 32
#define NW 32
#define ND 256
#define NPIX (NB*NH*NW)        // 16384

// output layout (floats): z_q [16,256,32,32] | kl | indices [16,32,32] | perplexity
#define ZQ_OFF  0
#define KL_OFF  4194304
#define IDX_OFF 4194305
#define PPL_OFF 4210689

#define LGAMMA_1024F 6071.2804f
#define BS_ROW_B 2080          // 16 rows x 1040 f16; chunk c at (c ^ (row&7))

typedef _Float16 f16x8 __attribute__((ext_vector_type(8)));
typedef _Float16 f16x4 __attribute__((ext_vector_type(4)));
typedef float    f32x4 __attribute__((ext_vector_type(4)));
typedef float    f32x2 __attribute__((ext_vector_type(2)));

__device__ __forceinline__ float fast_rcp(float x){ return __builtin_amdgcn_rcpf(x); }

// packed pair of independent elems: softplus -> alpha; Stirling lgamma/digamma
// (shift 3, z>=4) with log(prod) DEFERRED into prodAcc; e = (a/ln u)^2.
__device__ __forceinline__ f32x2 elem2(f32x2 x, f32x2 u,
                                       f32x2& S, f32x2& L, f32x2& P,
                                       f32x2& prodAcc){
    f32x2 t;   t[0] = __expf(-fabsf(x[0]));  t[1] = __expf(-fabsf(x[1]));
    f32x2 mx0; mx0[0] = fmaxf(x[0], 0.f);    mx0[1] = fmaxf(x[1], 0.f);
    f32x2 l1p; l1p[0] = __logf(1.f + t[0]);  l1p[1] = __logf(1.f + t[1]);
    f32x2 a  = mx0 + l1p + 1.f;
    f32x2 a1 = a + 1.f, a2 = a + 2.f, z = a + 3.f;
    f32x2 t12  = a1*a2;
    f32x2 prod = a*t12;
    f32x2 rz;  rz[0] = fast_rcp(z[0]);       rz[1] = fast_rcp(z[1]);
    f32x2 rp;  rp[0] = fast_rcp(prod[0]);    rp[1] = fast_rcp(prod[1]);
    f32x2 lz;  lz[0] = __logf(z[0]);         lz[1] = __logf(z[1]);
    prodAcc = prodAcc * prod;                // deferred: L -= log(prodAcc)
    f32x2 rz2 = rz*rz;
    f32x2 lg = (z - 0.5f)*lz - z + 0.918938533f
             + rz*(0.083333333f - 0.002777778f*rz2);
    f32x2 sr = (t12 + a*(a + a + 3.f))*rp;
    f32x2 dg = lz - 0.5f*rz - rz2*(0.083333333f - 0.008333333f*rz2) - sr;
    S += a; L += lg; P += (a - 1.f)*dg;
    f32x2 d = 1.f - u;
    f32x2 lup = -d*(1.f + d*(0.5f + d*(0.33333333f + d*(0.25f
              + d*(0.2f + d*(0.16666667f + d*0.14285714f))))));
    f32x2 lu;
    lu[0] = (d[0] < 0.09f) ? lup[0] : __logf(u[0]);
    lu[1] = (d[1] < 0.09f) ? lup[1] : __logf(u[1]);
    f32x2 ar; ar[0] = a[0]*fast_rcp(lu[0]);  ar[1] = a[1]*fast_rcp(lu[1]);
    return ar*ar;
}

// normalized f16 sample write: n = 256k+4nq+m -> chunk 32k+(nq>>1), sub 8(nq&1)+2m
__device__ __forceinline__ void bs_write(char* bsb, int wl, int nq,
                                         const float* ev, float zinv){
    char* brow = bsb + wl*BS_ROW_B;
    const int sw   = wl & 7;
    const int sub8 = (nq & 1) << 3;
    const int cb2  = nq >> 1;
#pragma unroll
    for (int k = 0; k < 4; ++k){
        f16x4 hv;
        hv[0] = (_Float16)(ev[4*k+0]*zinv);
        hv[1] = (_Float16)(ev[4*k+1]*zinv);
        hv[2] = (_Float16)(ev[4*k+2]*zinv);
        hv[3] = (_Float16)(ev[4*k+3]*zinv);
        *(f16x4*)(brow + (((32*k + cb2) ^ sw) << 4) + sub8) = hv;
    }
}

// ---------------------------------------------------------------------------
// k_tr: cb [1024n][256d] f32 -> cbT[kb][d][32kk] f16, natural K-order.
// ---------------------------------------------------------------------------
__global__ __launch_bounds__(256) void k_tr(
    const float* __restrict__ cb, _Float16* __restrict__ cbT)
{
    const int kb = blockIdx.x, kq = blockIdx.y, d = threadIdx.x;
    _Float16 tmp[8];
#pragma unroll
    for (int i = 0; i < 8; ++i)
        tmp[i] = (_Float16)cb[(size_t)(32*kb + 8*kq + i)*ND + d];
    *(f16x8*)(cbT + (size_t)kb*8192 + (size_t)d*32 + 8*kq) = *(f16x8*)tmp;
}

// ---------------------------------------------------------------------------
// k_mega: ONE block per row (512 blocks, single generation, 2/CU resident).
// Block processes BOTH 16-pixel halves of its row: phase-1 runs twice
// (asm-pinned loads, counted vmcnt; h1 loads stay in flight across a raw
// s_barrier with lgkmcnt-only drain), then ONE dual-B GEMM where each
// A-fragment feeds 2 MFMAs -> A L2-traffic halved.
// ---------------------------------------------------------------------------
__global__ __launch_bounds__(1024, 8) void k_mega(
    const float* __restrict__ logits, const float* __restrict__ noise,
    const _Float16* __restrict__ cbT, float* __restrict__ colpart,
    float* __restrict__ klpart, float* __restrict__ out)
{
    __shared__ __align__(16) char lds[32*BS_ROW_B + 12*256*4];
    char*  bsb0 = lds;
    char*  bsb1 = lds + 16*BS_ROW_B;
    float* redB = (float*)(lds + 32*BS_ROW_B);   // 2 banks x {S,L,P,Z,M,I}[256]

    const int t    = threadIdx.x;
    const int row  = blockIdx.x;                 // b*32 + h, 0..511
    const int b    = row >> 5, hh = row & 31;
    const int lane = t & 63;
    const int v    = t >> 6;                     // wave 0..15
    const int wl   = lane & 15;                  // pixel-in-half
    const int j4   = (lane >> 4) & 3;            // 0..3
    const int nq   = 4*v + j4;                   // 0..63; n = 256k + 4*nq + m

    const float* lgB0 = logits + (size_t)b*(NN*NH*NW) + (size_t)(4*nq)*(NH*NW)
                      + (size_t)hh*NW + wl;
    const float* nzB0 = noise  + (size_t)(row*32 + wl)*NN + 4*nq;
    const float* lgB1 = lgB0 + 16;
    const float* nzB1 = nzB0 + (size_t)16*NN;

    float ev[16];
    f32x2 SA, LA, PA, ZA, SB, LB, PB, ZB, prA, prB;
    float mxA, mxB;
    int   idxA, idxB;

    f32x4 u0, u1, u2, u3;
    float x00,x01,x02,x03, x10,x11,x12,x13;
    float x20,x21,x22,x23, x30,x31,x32,x33;
    f32x4 w0, w1, w2, w3;
    float y00,y01,y02,y03, y10,y11,y12,y13;
    float y20,y21,y22,y23, y30,y31,y32,y33;

#define NZ_ASM(U0,U1,U2,U3, NZP) \
    asm volatile( \
        "global_load_dwordx4 %0, %4, off\n\t" \
        "global_load_dwordx4 %1, %4, off offset:1024\n\t" \
        "global_load_dwordx4 %2, %4, off offset:2048\n\t" \
        "global_load_dwordx4 %3, %4, off offset:3072" \
        : "=&v"(U0), "=&v"(U1), "=&v"(U2), "=&v"(U3) : "v"(NZP))

#define LG_ASM(X0,X1,X2,X3, LGP, KK) \
    asm volatile( \
        "global_load_dword %0, %4, off offset:-4096\n\t" \
        "global_load_dword %1, %4, off\n\t" \
        "global_load_dword %2, %5, off offset:-4096\n\t" \
        "global_load_dword %3, %5, off" \
        : "=&v"(X0), "=&v"(X1), "=&v"(X2), "=&v"(X3) \
        : "v"((LGP) + (size_t)(256*(KK))*1024 + 1024), \
          "v"((LGP) + (size_t)(256*(KK))*1024 + 3072))

#define WAITV(NSTR) do{ asm volatile("s_waitcnt vmcnt(" NSTR ")"); \
                        __builtin_amdgcn_sched_barrier(0); }while(0)

#define BARRIER() do{ \
    __builtin_amdgcn_sched_barrier(0); \
    asm volatile("s_waitcnt lgkmcnt(0)" ::: "memory"); \
    __builtin_amdgcn_sched_barrier(0); \
    __builtin_amdgcn_s_barrier(); \
    __builtin_amdgcn_sched_barrier(0); }while(0)

#define STATS_INIT() do{ \
    SA = (f32x2)0.f; LA = (f32x2)0.f; PA = (f32x2)0.f; ZA = (f32x2)0.f; \
    SB = (f32x2)0.f; LB = (f32x2)0.f; PB = (f32x2)0.f; ZB = (f32x2)0.f; \
    prA = (f32x2)1.f; prB = (f32x2)1.f; \
    mxA = -1.f; mxB = -1.f; idxA = 0; idxB = 0; }while(0)

#define DO_PAIR(kk, X0,X1,X2,X3, UV) do{                          \
    f32x2 xA_, xB_, uA_, uB_;                                     \
    xA_[0]=X0; xA_[1]=X1; xB_[0]=X2; xB_[1]=X3;                   \
    uA_[0]=UV[0]; uA_[1]=UV[1]; uB_[0]=UV[2]; uB_[1]=UV[3];       \
    f32x2 eA = elem2(xA_, uA_, SA, LA, PA, prA);                  \
    f32x2 eB = elem2(xB_, uB_, SB, LB, PB, prB);                  \
    ZA += eA; ZB += eB;                                           \
    if (eA[0] > mxA){ mxA = eA[0]; idxA = 256*(kk) + 4*nq + 0; }  \
    if (eA[1] > mxA){ mxA = eA[1]; idxA = 256*(kk) + 4*nq + 1; }  \
    if (eB[0] > mxB){ mxB = eB[0]; idxB = 256*(kk) + 4*nq + 2; }  \
    if (eB[1] > mxB){ mxB = eB[1]; idxB = 256*(kk) + 4*nq + 3; }  \
    ev[4*(kk)+0]=eA[0]; ev[4*(kk)+1]=eA[1];                       \
    ev[4*(kk)+2]=eB[0]; ev[4*(kk)+3]=eB[1]; }while(0)

// merge packed accumulators + wave-reduce over j4 lanes + bank write
#define REDUCE_STORE(BANK) do{                                    \
    float S = (SA[0]+SA[1]) + (SB[0]+SB[1]);                      \
    float L = (LA[0]+LA[1]) + (LB[0]+LB[1])                       \
            - __logf(prA[0]*prA[1]) - __logf(prB[0]*prB[1]);      \
    float P = (PA[0]+PA[1]) + (PB[0]+PB[1]);                      \
    float Z = (ZA[0]+ZA[1]) + (ZB[0]+ZB[1]);                      \
    float mx; int idx;                                            \
    { bool take = (mxB > mxA) || (mxB == mxA && idxB < idxA);     \
      mx = take ? mxB : mxA; idx = take ? idxB : idxA; }          \
    _Pragma("unroll")                                             \
    for (int mask = 16; mask < 64; mask <<= 1){                   \
        S += __shfl_xor(S, mask);                                 \
        L += __shfl_xor(L, mask);                                 \
        P += __shfl_xor(P, mask);                                 \
        Z += __shfl_xor(Z, mask);                                 \
        float mo = __shfl_xor(mx, mask);                          \
        int   io = __shfl_xor(idx, mask);                         \
        bool take = (mo > mx) || (mo == mx && io < idx);          \
        mx = take ? mo : mx; idx = take ? io : idx;               \
    }                                                             \
    if (j4 == 0){                                                 \
        float* bk = redB + (BANK)*1536;                           \
        bk[       16*v + wl] = S;  bk[256  + 16*v + wl] = L;      \
        bk[512  + 16*v + wl] = P;  bk[768  + 16*v + wl] = Z;      \
        bk[1024 + 16*v + wl] = mx;                                \
        ((int*)bk)[1280 + 16*v + wl] = idx;                       \
    } }while(0)

    // ---- half 0: issue 20 loads, compute under counted vmcnt ----
    NZ_ASM(u0,u1,u2,u3, nzB0);
    LG_ASM(x00,x01,x02,x03, lgB0, 0);
    LG_ASM(x10,x11,x12,x13, lgB0, 1);
    LG_ASM(x20,x21,x22,x23, lgB0, 2);
    LG_ASM(x30,x31,x32,x33, lgB0, 3);

    STATS_INIT();
    WAITV("12"); DO_PAIR(0, x00,x01,x02,x03, u0);
    WAITV("8");  DO_PAIR(1, x10,x11,x12,x13, u1);
    WAITV("4");  DO_PAIR(2, x20,x21,x22,x23, u2);
    WAITV("0");  DO_PAIR(3, x30,x31,x32,x33, u3);
    REDUCE_STORE(0);

    // ---- issue half-1 loads; they stay in flight across barrier-1 ----
    NZ_ASM(w0,w1,w2,w3, nzB1);
    LG_ASM(y00,y01,y02,y03, lgB1, 0);
    LG_ASM(y10,y11,y12,y13, lgB1, 1);
    LG_ASM(y20,y21,y22,y23, lgB1, 2);
    LG_ASM(y30,y31,y32,y33, lgB1, 3);

    BARRIER();   // red bank0 visible (lgkm only; vmem stays outstanding)

    // ---- Bs0 write (consumes ev of half 0) ----
    {
        float Zt = 0.f;
#pragma unroll
        for (int q = 0; q < 16; ++q) Zt += redB[768 + 16*q + wl];
        bs_write(bsb0, wl, nq, ev, fast_rcp(Zt));
    }

    // ---- half 1 compute ----
    STATS_INIT();
    WAITV("12"); DO_PAIR(0, y00,y01,y02,y03, w0);
    WAITV("8");  DO_PAIR(1, y10,y11,y12,y13, w1);
    WAITV("4");  DO_PAIR(2, y20,y21,y22,y23, w2);
    WAITV("0");  DO_PAIR(3, y30,y31,y32,y33, w3);
    REDUCE_STORE(1);

    BARRIER();   // red bank1 + Bs0 visible

    {
        float Zt = 0.f;
#pragma unroll
        for (int q = 0; q < 16; ++q) Zt += redB[1536 + 768 + 16*q + wl];
        bs_write(bsb1, wl, nq, ev, fast_rcp(Zt));
    }

    BARRIER();   // Bs1 visible: GEMM may read both halves

    // ---- GEMM: one A-fragment feeds TWO MFMAs (B of both halves) ----
    const _Float16* aBase = cbT + (size_t)(16*v + wl)*32 + j4*8;
    const char* bRow0 = bsb0 + wl*BS_ROW_B;
    const char* bRow1 = bsb1 + wl*BS_ROW_B;
    const int fsw = wl & 7;

    f32x4 acc0 = (f32x4)0.f, acc1 = (f32x4)0.f;
    f16x8 ar[4];
    ar[0] = *(const f16x8*)(aBase);
    ar[1] = *(const f16x8*)(aBase + 8192);
    ar[2] = *(const f16x8*)(aBase + 2*8192);
    __builtin_amdgcn_sched_barrier(0);

#pragma unroll
    for (int kb = 0; kb < 32; ++kb){
        if (kb + 3 < 32){
            ar[(kb+3)&3] = *(const f16x8*)(aBase + (size_t)(kb+3)*8192);
            __builtin_amdgcn_sched_barrier(0);
        }
        const int boff = (((kb << 2) | j4) ^ fsw) << 4;
        f16x8 bf0 = *(const f16x8*)(bRow0 + boff);
        f16x8 bf1 = *(const f16x8*)(bRow1 + boff);
        acc0 = __builtin_amdgcn_mfma_f32_16x16x32_f16(ar[kb&3], bf0, acc0, 0, 0, 0);
        acc1 = __builtin_amdgcn_mfma_f32_16x16x32_f16(ar[kb&3], bf1, acc1, 0, 0, 0);
    }

    float* outp = out + (size_t)b*(ND*1024) + hh*32;
#pragma unroll
    for (int r = 0; r < 4; ++r){
        int d = 16*v + 4*j4 + r;
        outp[(size_t)d*1024 + wl]      = acc0[r];
        outp[(size_t)d*1024 + 16 + wl] = acc1[r];
    }

    // ---- colsum: thread t sums column t over all 32 pixel rows ----
    {
        float s0 = 0.f;
#pragma unroll
        for (int r = 0; r < 16; ++r){
            const int off = ((((t >> 3) ^ (r & 7)) << 4) + 2*(t & 7));
            s0 += (float)*(const _Float16*)(bsb0 + r*BS_ROW_B + off);
            s0 += (float)*(const _Float16*)(bsb1 + r*BS_ROW_B + off);
        }
        colpart[(size_t)row*NN + t] = s0;
    }

    // ---- per-pixel finalize: kl + argmax for both halves ----
    if (t < 16){
        float klb = 0.f;
#pragma unroll
        for (int h2 = 0; h2 < 2; ++h2){
            const float* bk = redB + h2*1536;
            const int*  bkI = (const int*)bk;
            float Sq = 0.f, Lq = 0.f, Pq = 0.f, M = -1.f;
            int I = 0x7fffffff;
#pragma unroll
            for (int q = 0; q < 16; ++q){
                Sq += bk[16*q + t]; Lq += bk[256 + 16*q + t];
                Pq += bk[512 + 16*q + t];
                float m = bk[1024 + 16*q + t]; int i = bkI[1280 + 16*q + t];
                bool take = (m > M) || (m == M && i < I);
                M = take ? m : M; I = take ? i : I;
            }
            out[IDX_OFF + row*32 + 16*h2 + t] = (float)I;
            float rS  = fast_rcp(Sq);
            float lnS = __logf(Sq);
            float lgS = (Sq - 0.5f)*lnS - Sq + 0.918938533f + 0.083333333f*rS;
            float dgS = lnS - 0.5f*rS;
            float kl = lgS - Lq - LGAMMA_1024F + (Pq - dgS*(Sq - 1024.f));
#pragma unroll
            for (int mask = 1; mask < 16; mask <<= 1) kl += __shfl_xor(kl, mask);
            klb += kl;
        }
        if (t == 0) klpart[row] = klb;
    }
#undef NZ_ASM
#undef LG_ASM
#undef WAITV
#undef BARRIER
#undef STATS_INIT
#undef DO_PAIR
#undef REDUCE_STORE
}

// ---------------------------------------------------------------------------
// k_red: colsum[n] = sum over 512 colpart rows. 32 blocks x 32 n-cols;
// 8 row-segments of 64 reduced through LDS.
// ---------------------------------------------------------------------------
__global__ __launch_bounds__(256) void k_red(
    const float* __restrict__ colpart, float* __restrict__ colsum)
{
    __shared__ float red[8][32];
    const int nl = threadIdx.x & 31;
    const int rs = threadIdx.x >> 5;             // 0..7
    const int n  = blockIdx.x*32 + nl;
    const float* cp = colpart + (size_t)(rs*64)*NN + n;
    float s = 0.f;
#pragma unroll 8
    for (int r = 0; r < 64; ++r)
        s += cp[(size_t)r*NN];
    red[rs][nl] = s;
    __syncthreads();
    if (threadIdx.x < 32){
        float tot = 0.f;
#pragma unroll
        for (int i = 0; i < 8; ++i) tot += red[i][threadIdx.x];
        colsum[blockIdx.x*32 + threadIdx.x] = tot;
    }
}

// ---------------------------------------------------------------------------
// k_final: kl_loss (from klpart[512]) + perplexity (from colsum[1024])
// ---------------------------------------------------------------------------
__global__ __launch_bounds__(256) void k_final(
    const float* __restrict__ colsum, const float* __restrict__ klpart,
    float* __restrict__ out)
{
    __shared__ float red[8];
    const int tid = threadIdx.x;
    float s = 0.f, kls = 0.f;
#pragma unroll
    for (int n = tid; n < NN; n += 256){
        float avg = colsum[n] * (1.f/16384.f);
        s += avg * logf(avg + 1e-10f);
        if (n < 512) kls += klpart[n];
    }
#pragma unroll
    for (int mask = 1; mask < 64; mask <<= 1){
        s   += __shfl_xor(s, mask);
        kls += __shfl_xor(kls, mask);
    }
    if ((tid & 63) == 0){ red[tid >> 6] = s; red[4 + (tid >> 6)] = kls; }
    __syncthreads();
    if (tid == 0){
        float tot = red[0] + red[1] + red[2] + red[3];
        float klt = red[4] + red[5] + red[6] + red[7];
        out[PPL_OFF] = expf(-tot);
        out[KL_OFF]  = 1e-3f * (klt * (1.f/16384.f));
    }
}

extern "C" void kernel_launch(void* const* d_in, const int* in_sizes, int n_in,
                              void* d_out, int out_size, void* d_ws, size_t ws_size,
                              hipStream_t stream)
{
    const float* logits = (const float*)d_in[0];
    const float* cb     = (const float*)d_in[1];
    const float* noise  = (const float*)d_in[2];
    float* out = (float*)d_out;

    float* colpart = (float*)d_ws;                       // 512*1024 f32 = 2 MB
    float* colsum  = colpart + (size_t)512*NN;           // 1024
    float* klpart  = colsum + NN;                        // 512 (pad to 1024)
    _Float16* cbT  = (_Float16*)(klpart + 1024);         // 512 KB (16B-aligned)

    k_tr   <<<dim3(32, 4), 256, 0, stream>>>(cb, cbT);
    k_mega <<<dim3(512), 1024, 0, stream>>>(logits, noise, cbT, colpart, klpart, out);
    k_red  <<<dim3(32),    256, 0, stream>>>(colpart, colsum);
    k_final<<<1, 256, 0, stream>>>(colsum, klpart, out);
}

// Round 8
// 214.590 us; speedup vs baseline: 1.0713x; 1.0713x over previous
//
#include <hip/hip_runtime.h>
#include <math.h>

#define NB 16
#define NN 1024
#define NH 32
#define NW 32
#define ND 256
#define NPIX (NB*NH*NW)        // 16384

// output layout (floats): z_q [16,256,32,32] | kl | indices [16,32,32] | perplexity
#define ZQ_OFF  0
#define KL_OFF  4194304
#define IDX_OFF 4194305
#define PPL_OFF 4210689

#define LGAMMA_1024F 6071.2804f
#define BS_ROW_B 2080          // 16 rows x 1040 f16; chunk c at (c ^ (row&7))

typedef _Float16 f16x8 __attribute__((ext_vector_type(8)));
typedef _Float16 f16x4 __attribute__((ext_vector_type(4)));
typedef float    f32x4 __attribute__((ext_vector_type(4)));
typedef float    f32x2 __attribute__((ext_vector_type(2)));

__device__ __forceinline__ float fast_rcp(float x){ return __builtin_amdgcn_rcpf(x); }

// packed pair of independent elems: softplus -> alpha; Stirling lgamma/digamma
// (shift 3, z>=4) with log(prod) DEFERRED into prodAcc (caller subtracts
// log(prodAcc) from L once); e = (a/ln u)^2.
// All poly/Stirling arithmetic is float2 -> VOP3P v_pk_* ops.
__device__ __forceinline__ f32x2 elem2(f32x2 x, f32x2 u,
                                       f32x2& S, f32x2& L, f32x2& P,
                                       f32x2& prodAcc){
    f32x2 t;   t[0] = __expf(-fabsf(x[0]));  t[1] = __expf(-fabsf(x[1]));
    f32x2 mx0; mx0[0] = fmaxf(x[0], 0.f);    mx0[1] = fmaxf(x[1], 0.f);
    f32x2 l1p; l1p[0] = __logf(1.f + t[0]);  l1p[1] = __logf(1.f + t[1]);
    f32x2 a  = mx0 + l1p + 1.f;
    f32x2 a1 = a + 1.f, a2 = a + 2.f, z = a + 3.f;
    f32x2 t12  = a1*a2;
    f32x2 prod = a*t12;
    f32x2 rz;  rz[0] = fast_rcp(z[0]);       rz[1] = fast_rcp(z[1]);
    f32x2 rp;  rp[0] = fast_rcp(prod[0]);    rp[1] = fast_rcp(prod[1]);
    f32x2 lz;  lz[0] = __logf(z[0]);         lz[1] = __logf(z[1]);
    prodAcc = prodAcc * prod;                // deferred: L -= log(prodAcc)
    f32x2 rz2 = rz*rz;
    f32x2 lg = (z - 0.5f)*lz - z + 0.918938533f
             + rz*(0.083333333f - 0.002777778f*rz2);
    f32x2 sr = (t12 + a*(a + a + 3.f))*rp;
    f32x2 dg = lz - 0.5f*rz - rz2*(0.083333333f - 0.008333333f*rz2) - sr;
    S += a; L += lg; P += (a - 1.f)*dg;
    f32x2 d = 1.f - u;
    f32x2 lup = -d*(1.f + d*(0.5f + d*(0.33333333f + d*(0.25f
              + d*(0.2f + d*(0.16666667f + d*0.14285714f))))));
    f32x2 lu;
    lu[0] = (d[0] < 0.09f) ? lup[0] : __logf(u[0]);
    lu[1] = (d[1] < 0.09f) ? lup[1] : __logf(u[1]);
    f32x2 ar; ar[0] = a[0]*fast_rcp(lu[0]);  ar[1] = a[1]*fast_rcp(lu[1]);
    return ar*ar;
}

// ---------------------------------------------------------------------------
// k_tr: cb [1024n][256d] f32 -> cbT[kb][d][32kk] f16, natural K-order.
// ---------------------------------------------------------------------------
__global__ __launch_bounds__(256) void k_tr(
    const float* __restrict__ cb, _Float16* __restrict__ cbT)
{
    const int kb = blockIdx.x, kq = blockIdx.y, d = threadIdx.x;
    _Float16 tmp[8];
#pragma unroll
    for (int i = 0; i < 8; ++i)
        tmp[i] = (_Float16)cb[(size_t)(32*kb + 8*kq + i)*ND + d];
    *(f16x8*)(cbT + (size_t)kb*8192 + (size_t)d*32 + 8*kq) = *(f16x8*)tmp;
}

// ---------------------------------------------------------------------------
// k_mega: 1024 threads, 16 pixels, 64 n-lane-groups/pixel.
// Thread owns n = 256k + 4*nq + m, nq = 4v+j4 in [0,64), k<4, m<4.
// Phase-1 loads asm-pinned (issued up-front, consumed under counted vmcnt);
// elem math packed 2-wide; GEMM a-ring prefetch pinned with sched_barrier
// (round-5 schedule restored).
// ---------------------------------------------------------------------------
__global__ __launch_bounds__(1024, 2) void k_mega(
    const float* __restrict__ logits, const float* __restrict__ noise,
    const _Float16* __restrict__ cbT, float* __restrict__ colpart,
    float* __restrict__ klpart, float* __restrict__ out)
{
    __shared__ __align__(16) char lds[16*BS_ROW_B + 6*256*4];
    char*  bsb  = lds;
    float* redS = (float*)(lds + 16*BS_ROW_B);   // [16][16]
    float* redL = redS + 256;
    float* redP = redL + 256;
    float* redZ = redP + 256;
    float* redM = redZ + 256;
    int*   redI = (int*)(redM + 256);

    const int t    = threadIdx.x;
    const int row  = blockIdx.x >> 1;            // b*32 + h
    const int w0   = (blockIdx.x & 1) * 16;
    const int b    = row >> 5, h = row & 31;
    const int lane = t & 63;
    const int v    = t >> 6;                     // wave 0..15
    const int wl   = lane & 15;                  // pixel-in-block
    const int j4   = (lane >> 4) & 3;            // 0..3
    const int p    = row*32 + w0 + wl;
    const int nq   = 4*v + j4;                   // 0..63; n = 256k + 4*nq + m

    const float* lgB = logits + (size_t)b*(NN*NH*NW) + (size_t)(4*nq)*(NH*NW)
                     + (size_t)h*NW + w0 + wl;
    const float* nzB = noise  + (size_t)p*NN + 4*nq;

    f32x4 u0, u1, u2, u3;
    float x00,x01,x02,x03, x10,x11,x12,x13;
    float x20,x21,x22,x23, x30,x31,x32,x33;
    float ev[16];
    // packed accumulators: A covers m=0,1; B covers m=2,3 (per chunk)
    f32x2 SA = (f32x2)0.f, LA = (f32x2)0.f, PA = (f32x2)0.f, ZA = (f32x2)0.f;
    f32x2 SB = (f32x2)0.f, LB = (f32x2)0.f, PB = (f32x2)0.f, ZB = (f32x2)0.f;
    f32x2 prA = (f32x2)1.f, prB = (f32x2)1.f;
    float mxA = -1.f, mxB = -1.f;
    int   idxA = 0, idxB = 0;

    // ---- issue ALL phase-1 loads (asm: cannot be sunk/split) ----
    asm volatile(
        "global_load_dwordx4 %0, %4, off\n\t"
        "global_load_dwordx4 %1, %4, off offset:1024\n\t"
        "global_load_dwordx4 %2, %4, off offset:2048\n\t"
        "global_load_dwordx4 %3, %4, off offset:3072"
        : "=&v"(u0), "=&v"(u1), "=&v"(u2), "=&v"(u3)
        : "v"(nzB));

    // logits chunk k: elems at lgB + (256k+m)*1024 floats, m=0..3
#define LG_ASM(X0,X1,X2,X3,KK) \
    asm volatile( \
        "global_load_dword %0, %4, off offset:-4096\n\t" \
        "global_load_dword %1, %4, off\n\t" \
        "global_load_dword %2, %5, off offset:-4096\n\t" \
        "global_load_dword %3, %5, off" \
        : "=&v"(X0), "=&v"(X1), "=&v"(X2), "=&v"(X3) \
        : "v"(lgB + (size_t)(256*(KK))*1024 + 1024), \
          "v"(lgB + (size_t)(256*(KK))*1024 + 3072))

    LG_ASM(x00,x01,x02,x03, 0);
    LG_ASM(x10,x11,x12,x13, 1);
    LG_ASM(x20,x21,x22,x23, 2);
    LG_ASM(x30,x31,x32,x33, 3);
#undef LG_ASM

#define WAITV(NSTR) do{ asm volatile("s_waitcnt vmcnt(" NSTR ")"); \
                        __builtin_amdgcn_sched_barrier(0); }while(0)

#define DO_PAIR(kk, X0,X1,X2,X3, UV) do{                          \
    f32x2 xA_, xB_, uA_, uB_;                                     \
    xA_[0]=X0; xA_[1]=X1; xB_[0]=X2; xB_[1]=X3;                   \
    uA_[0]=UV[0]; uA_[1]=UV[1]; uB_[0]=UV[2]; uB_[1]=UV[3];       \
    f32x2 eA = elem2(xA_, uA_, SA, LA, PA, prA);                  \
    f32x2 eB = elem2(xB_, uB_, SB, LB, PB, prB);                  \
    ZA += eA; ZB += eB;                                           \
    if (eA[0] > mxA){ mxA = eA[0]; idxA = 256*(kk) + 4*nq + 0; }  \
    if (eA[1] > mxA){ mxA = eA[1]; idxA = 256*(kk) + 4*nq + 1; }  \
    if (eB[0] > mxB){ mxB = eB[0]; idxB = 256*(kk) + 4*nq + 2; }  \
    if (eB[1] > mxB){ mxB = eB[1]; idxB = 256*(kk) + 4*nq + 3; }  \
    ev[4*(kk)+0]=eA[0]; ev[4*(kk)+1]=eA[1];                       \
    ev[4*(kk)+2]=eB[0]; ev[4*(kk)+3]=eB[1]; }while(0)

    WAITV("12");   // noise#0 + lg chunk0 complete
    DO_PAIR(0, x00,x01,x02,x03, u0);
    WAITV("8");
    DO_PAIR(1, x10,x11,x12,x13, u1);
    WAITV("4");
    DO_PAIR(2, x20,x21,x22,x23, u2);
    WAITV("0");
    DO_PAIR(3, x30,x31,x32,x33, u3);
#undef WAITV
#undef DO_PAIR

    // merge packed accumulator sets (batched logs: 2 per thread)
    float S = (SA[0] + SA[1]) + (SB[0] + SB[1]);
    float L = (LA[0] + LA[1]) + (LB[0] + LB[1])
            - __logf(prA[0]*prA[1]) - __logf(prB[0]*prB[1]);
    float P = (PA[0] + PA[1]) + (PB[0] + PB[1]);
    float Z = (ZA[0] + ZA[1]) + (ZB[0] + ZB[1]);
    float mx; int idx;
    {
        bool take = (mxB > mxA) || (mxB == mxA && idxB < idxA);
        mx  = take ? mxB : mxA;
        idx = take ? idxB : idxA;
    }

    // reduce over the 4 j4-lanes of this pixel within the wave
#pragma unroll
    for (int mask = 16; mask < 64; mask <<= 1){
        S += __shfl_xor(S, mask);
        L += __shfl_xor(L, mask);
        P += __shfl_xor(P, mask);
        Z += __shfl_xor(Z, mask);
        float mo = __shfl_xor(mx, mask);
        int   io = __shfl_xor(idx, mask);
        bool take = (mo > mx) || (mo == mx && io < idx);
        mx  = take ? mo : mx;
        idx = take ? io : idx;
    }
    if (j4 == 0){
        redS[16*v + wl] = S;  redL[16*v + wl] = L;
        redP[16*v + wl] = P;  redZ[16*v + wl] = Z;
        redM[16*v + wl] = mx; redI[16*v + wl] = idx;
    }
    __syncthreads();

    // every thread: full Z for its pixel (16 broadcast LDS reads)
    float Zt = 0.f;
#pragma unroll
    for (int qz = 0; qz < 16; ++qz) Zt += redZ[16*qz + wl];
    const float zinv = fast_rcp(Zt);

    // write normalized f16 sample to Bs as 8B ds_write_b64:
    // n = 256k + 4*nq + m -> chunk c = 32k + (nq>>1), sub byte = 8*(nq&1)+2m
    {
        char* brow = bsb + wl*BS_ROW_B;
        const int sw   = wl & 7;
        const int sub8 = (nq & 1) << 3;
        const int cb2  = nq >> 1;
#pragma unroll
        for (int k = 0; k < 4; ++k){
            f16x4 hv;
            hv[0] = (_Float16)(ev[4*k+0]*zinv);
            hv[1] = (_Float16)(ev[4*k+1]*zinv);
            hv[2] = (_Float16)(ev[4*k+2]*zinv);
            hv[3] = (_Float16)(ev[4*k+3]*zinv);
            *(f16x4*)(brow + (((32*k + cb2) ^ sw) << 4) + sub8) = hv;
        }
    }
    __syncthreads();   // Bs complete

    // ---- GEMM: D[d][pix] = cbT(d,K)*Bs(pix,K); wave v -> d in [16v,16v+16) ----
    // depth-3 a-prefetch (4-buffer ring), pinned (round-5 schedule).
    const _Float16* aBase = cbT + (size_t)(16*v + wl)*32 + j4*8;
    const char* bRow = bsb + wl*BS_ROW_B;
    const int fsw = wl & 7;

    f32x4 acc = (f32x4)0.f;
    f16x8 ar[4];
    ar[0] = *(const f16x8*)(aBase);
    ar[1] = *(const f16x8*)(aBase + 8192);
    ar[2] = *(const f16x8*)(aBase + 2*8192);
    __builtin_amdgcn_sched_barrier(0);

#pragma unroll
    for (int kb = 0; kb < 32; ++kb){
        if (kb + 3 < 32){
            ar[(kb+3)&3] = *(const f16x8*)(aBase + (size_t)(kb+3)*8192);
            __builtin_amdgcn_sched_barrier(0);
        }
        f16x8 bf = *(const f16x8*)(bRow + ((((kb << 2) | j4) ^ fsw) << 4));
        acc = __builtin_amdgcn_mfma_f32_16x16x32_f16(ar[kb&3], bf, acc, 0, 0, 0);
    }

    float* outp = out + (size_t)b*(ND*1024) + h*32 + w0;
#pragma unroll
    for (int r = 0; r < 4; ++r){
        int d = 16*v + 4*j4 + r;
        outp[(size_t)d*1024 + wl] = acc[r];
    }

    // ---- colsum row for this block: thread t sums column t ----
    {
        float s0 = 0.f;
#pragma unroll
        for (int r = 0; r < 16; ++r){
            const char* br = bsb + r*BS_ROW_B;
            const int sw2 = r & 7;
            s0 += (float)*(const _Float16*)(br + ((((t >> 3) ^ sw2) << 4) + 2*(t & 7)));
        }
        colpart[(size_t)blockIdx.x*NN + t] = s0;
    }

    // per-pixel finalize: kl, argmax index (off the barrier critical path)
    if (t < 16){
        float Sq = 0.f, Lq = 0.f, Pq = 0.f, M = -1.f;
        int I = 0x7fffffff;
#pragma unroll
        for (int qz = 0; qz < 16; ++qz){
            Sq += redS[16*qz + t]; Lq += redL[16*qz + t]; Pq += redP[16*qz + t];
            float m = redM[16*qz + t]; int i = redI[16*qz + t];
            bool take = (m > M) || (m == M && i < I);
            M = take ? m : M; I = take ? i : I;
        }
        out[IDX_OFF + row*32 + w0 + t] = (float)I;
        float rS  = fast_rcp(Sq);
        float lnS = __logf(Sq);
        float lgS = (Sq - 0.5f)*lnS - Sq + 0.918938533f + 0.083333333f*rS;
        float dgS = lnS - 0.5f*rS;
        float kl = lgS - Lq - LGAMMA_1024F + (Pq - dgS*(Sq - 1024.f));
#pragma unroll
        for (int mask = 1; mask < 16; mask <<= 1) kl += __shfl_xor(kl, mask);
        if (t == 0) klpart[blockIdx.x] = kl;
    }
}

// ---------------------------------------------------------------------------
// k_red: colsum[n] = sum over 1024 colpart rows. Atomic-free: 32 blocks,
// each owns 32 n-columns fully; 8 row-segments reduced through LDS.
// ---------------------------------------------------------------------------
__global__ __launch_bounds__(256) void k_red(
    const float* __restrict__ colpart, float* __restrict__ colsum)
{
    __shared__ float red[8][32];
    const int nl = threadIdx.x & 31;
    const int rs = threadIdx.x >> 5;             // 0..7
    const int n  = blockIdx.x*32 + nl;
    const float* cp = colpart + (size_t)rs*128*NN + n;
    float s = 0.f;
#pragma unroll 8
    for (int r = 0; r < 128; ++r)
        s += cp[(size_t)r*NN];
    red[rs][nl] = s;
    __syncthreads();
    if (threadIdx.x < 32){
        float tot = 0.f;
#pragma unroll
        for (int i = 0; i < 8; ++i) tot += red[i][threadIdx.x];
        colsum[blockIdx.x*32 + threadIdx.x] = tot;
    }
}

// ---------------------------------------------------------------------------
// k_final: kl_loss (from klpart[1024]) + perplexity (from colsum[1024])
// ---------------------------------------------------------------------------
__global__ __launch_bounds__(256) void k_final(
    const float* __restrict__ colsum, const float* __restrict__ klpart,
    float* __restrict__ out)
{
    __shared__ float red[8];
    const int tid = threadIdx.x;
    float s = 0.f, kls = 0.f;
#pragma unroll
    for (int n = tid; n < NN; n += 256){
        float avg = colsum[n] * (1.f/16384.f);
        s += avg * logf(avg + 1e-10f);
        kls += klpart[n];
    }
#pragma unroll
    for (int mask = 1; mask < 64; mask <<= 1){
        s   += __shfl_xor(s, mask);
        kls += __shfl_xor(kls, mask);
    }
    if ((tid & 63) == 0){ red[tid >> 6] = s; red[4 + (tid >> 6)] = kls; }
    __syncthreads();
    if (tid == 0){
        float tot = red[0] + red[1] + red[2] + red[3];
        float klt = red[4] + red[5] + red[6] + red[7];
        out[PPL_OFF] = expf(-tot);
        out[KL_OFF]  = 1e-3f * (klt * (1.f/16384.f));
    }
}

extern "C" void kernel_launch(void* const* d_in, const int* in_sizes, int n_in,
                              void* d_out, int out_size, void* d_ws, size_t ws_size,
                              hipStream_t stream)
{
    const float* logits = (const float*)d_in[0];
    const float* cb     = (const float*)d_in[1];
    const float* noise  = (const float*)d_in[2];
    float* out = (float*)d_out;

    float* colpart = (float*)d_ws;                       // 1024*1024 f32 = 4 MB
    float* colsum  = colpart + (size_t)1024*NN;          // 1024
    float* klpart  = colsum + NN;                        // 1024
    _Float16* cbT  = (_Float16*)(klpart + NN);           // 512 KB (16B-aligned)

    k_tr   <<<dim3(32, 4), 256, 0, stream>>>(cb, cbT);
    k_mega <<<dim3(1024), 1024, 0, stream>>>(logits, noise, cbT, colpart, klpart, out);
    k_red  <<<dim3(32),    256, 0, stream>>>(colpart, colsum);
    k_final<<<1, 256, 0, stream>>>(colsum, klpart, out);
}

// Round 9
// 204.302 us; speedup vs baseline: 1.1252x; 1.0504x over previous
//
#include <hip/hip_runtime.h>
#include <math.h>

#define NB 16
#define NN 1024
#define NH 32
#define NW 32
#define ND 256
#define NPIX (NB*NH*NW)        // 16384

// output layout (floats): z_q [16,256,32,32] | kl | indices [16,32,32] | perplexity
#define ZQ_OFF  0
#define KL_OFF  4194304
#define IDX_OFF 4194305
#define PPL_OFF 4210689

#define LGAMMA_1024F 6071.2804f
// 16 rows x 2096 B; 131 (16B-groups) == 3 mod 8 -> rows spread over all banks
#define BS_ROW_B 2096

typedef _Float16 f16x8 __attribute__((ext_vector_type(8)));
typedef _Float16 f16x4 __attribute__((ext_vector_type(4)));
typedef float    f32x4 __attribute__((ext_vector_type(4)));

__device__ __forceinline__ float fast_rcp(float x){ return __builtin_amdgcn_rcpf(x); }

// one element: alpha, stats accumulation, e = (a/ln u)^2.
// lgamma's log(prod) is DEFERRED: pr *= a(a+1)(a+2); caller subtracts
// log(pr) once per 8-elem chain (16 logs -> 2 per thread).
__device__ __forceinline__ float elem(float x, float u,
                                      float& S, float& L, float& P, float& pr){
    float t  = __expf(-fabsf(x));
    float a  = fmaxf(x, 0.f) + __logf(1.f + t) + 1.f;
    float a1 = a + 1.f, a2 = a + 2.f, z = a + 3.f;
    float t12  = a1*a2;
    float prod = a*t12;
    float rz = fast_rcp(z);
    float rp = fast_rcp(prod);
    float lz = __logf(z);
    pr *= prod;
    float rz2 = rz*rz;
    float lg = (z - 0.5f)*lz - z + 0.918938533f
             + rz*(0.083333333f - 0.002777778f*rz2);
    float sr = (t12 + a*(a + a + 3.f))*rp;
    float dg = lz - 0.5f*rz - rz2*(0.083333333f - 0.008333333f*rz2) - sr;
    S += a; L += lg; P += (a - 1.f)*dg;
    float d = 1.f - u;
    float lup = -d*(1.f + d*(0.5f + d*(0.33333333f + d*(0.25f
              + d*(0.2f + d*(0.16666667f + d*0.14285714f))))));
    float lu = (d < 0.09f) ? lup : __logf(u);
    float ar = a * fast_rcp(lu);
    return ar*ar;
}

// ---------------------------------------------------------------------------
// k_tr: cb [1024n][256d] f32 -> cbT[kb][d][32kk] f16, natural K-order.
// Also zeroes the done-counter for k_redfinal (re-zeroed every graph replay).
// ---------------------------------------------------------------------------
__global__ __launch_bounds__(256) void k_tr(
    const float* __restrict__ cb, _Float16* __restrict__ cbT,
    unsigned int* __restrict__ done)
{
    const int kb = blockIdx.x, kq = blockIdx.y, d = threadIdx.x;
    if (kb == 0 && kq == 0 && d == 0) *done = 0u;
    _Float16 tmp[8];
#pragma unroll
    for (int i = 0; i < 8; ++i)
        tmp[i] = (_Float16)cb[(size_t)(32*kb + 8*kq + i)*ND + d];
    *(f16x8*)(cbT + (size_t)kb*8192 + (size_t)d*32 + 8*kq) = *(f16x8*)tmp;
}

// ---------------------------------------------------------------------------
// k_mega: 1024 threads, 16 pixels, 64 n-lane-groups/pixel (round-5 champion).
// Thread owns n = 256k + 4*nq + m, nq = 4v+j4 in [0,64), k<4, m<4.
// Phase-1 loads asm-pinned (issued up-front, consumed under counted vmcnt);
// scalar elem math (VGPR-32 regime) + deferred-log merge.
// ---------------------------------------------------------------------------
__global__ __launch_bounds__(1024, 2) void k_mega(
    const float* __restrict__ logits, const float* __restrict__ noise,
    const _Float16* __restrict__ cbT, float* __restrict__ colpart,
    float* __restrict__ klpart, float* __restrict__ out)
{
    __shared__ __align__(16) char lds[16*BS_ROW_B + 6*256*4];
    char*  bsb  = lds;
    float* redS = (float*)(lds + 16*BS_ROW_B);   // [16][16]
    float* redL = redS + 256;
    float* redP = redL + 256;
    float* redZ = redP + 256;
    float* redM = redZ + 256;
    int*   redI = (int*)(redM + 256);

    const int t    = threadIdx.x;
    const int row  = blockIdx.x >> 1;            // b*32 + h
    const int w0   = (blockIdx.x & 1) * 16;
    const int b    = row >> 5, h = row & 31;
    const int lane = t & 63;
    const int v    = t >> 6;                     // wave 0..15
    const int wl   = lane & 15;                  // pixel-in-block
    const int j4   = (lane >> 4) & 3;            // 0..3
    const int p    = row*32 + w0 + wl;
    const int nq   = 4*v + j4;                   // 0..63; n = 256k + 4*nq + m

    const float* lgB = logits + (size_t)b*(NN*NH*NW) + (size_t)(4*nq)*(NH*NW)
                     + (size_t)h*NW + w0 + wl;
    const float* nzB = noise  + (size_t)p*NN + 4*nq;

    f32x4 u0, u1, u2, u3;
    float x00,x01,x02,x03, x10,x11,x12,x13;
    float x20,x21,x22,x23, x30,x31,x32,x33;
    float ev[16];
    // 2-way split accumulators (halve serial FP chains); pr per 8-elem chain
    float Sa = 0.f, La = 0.f, Pa = 0.f, Za = 0.f, prA = 1.f;
    float Sb = 0.f, Lb = 0.f, Pb = 0.f, Zb = 0.f, prB = 1.f;
    float mxA = -1.f, mxB = -1.f;
    int   idxA = 0, idxB = 0;

    // ---- issue ALL phase-1 loads (asm: cannot be sunk/split) ----
    asm volatile(
        "global_load_dwordx4 %0, %4, off\n\t"
        "global_load_dwordx4 %1, %4, off offset:1024\n\t"
        "global_load_dwordx4 %2, %4, off offset:2048\n\t"
        "global_load_dwordx4 %3, %4, off offset:3072"
        : "=&v"(u0), "=&v"(u1), "=&v"(u2), "=&v"(u3)
        : "v"(nzB));

    // logits chunk k: elems at lgB + (256k+m)*1024 floats, m=0..3
#define LG_ASM(X0,X1,X2,X3,KK) \
    asm volatile( \
        "global_load_dword %0, %4, off offset:-4096\n\t" \
        "global_load_dword %1, %4, off\n\t" \
        "global_load_dword %2, %5, off offset:-4096\n\t" \
        "global_load_dword %3, %5, off" \
        : "=&v"(X0), "=&v"(X1), "=&v"(X2), "=&v"(X3) \
        : "v"(lgB + (size_t)(256*(KK))*1024 + 1024), \
          "v"(lgB + (size_t)(256*(KK))*1024 + 3072))

    LG_ASM(x00,x01,x02,x03, 0);
    LG_ASM(x10,x11,x12,x13, 1);
    LG_ASM(x20,x21,x22,x23, 2);
    LG_ASM(x30,x31,x32,x33, 3);
#undef LG_ASM

#define WAITV(NSTR) do{ asm volatile("s_waitcnt vmcnt(" NSTR ")"); \
                        __builtin_amdgcn_sched_barrier(0); }while(0)

#define DO_EA(kk,mm,X,UC) do{                                     \
    float e = elem(X, UC, Sa, La, Pa, prA);                       \
    Za += e;                                                      \
    if (e > mxA){ mxA = e; idxA = 256*(kk) + 4*nq + (mm); }       \
    ev[4*(kk)+(mm)] = e; }while(0)

#define DO_EB(kk,mm,X,UC) do{                                     \
    float e = elem(X, UC, Sb, Lb, Pb, prB);                       \
    Zb += e;                                                      \
    if (e > mxB){ mxB = e; idxB = 256*(kk) + 4*nq + (mm); }       \
    ev[4*(kk)+(mm)] = e; }while(0)

    WAITV("12");   // noise#0 + lg chunk0 complete
    DO_EA(0,0,x00,u0[0]); DO_EB(0,1,x01,u0[1]);
    DO_EA(0,2,x02,u0[2]); DO_EB(0,3,x03,u0[3]);
    WAITV("8");    // noise#1 + lg chunk1 complete
    DO_EA(1,0,x10,u1[0]); DO_EB(1,1,x11,u1[1]);
    DO_EA(1,2,x12,u1[2]); DO_EB(1,3,x13,u1[3]);
    WAITV("4");
    DO_EA(2,0,x20,u2[0]); DO_EB(2,1,x21,u2[1]);
    DO_EA(2,2,x22,u2[2]); DO_EB(2,3,x23,u2[3]);
    WAITV("0");
    DO_EA(3,0,x30,u3[0]); DO_EB(3,1,x31,u3[1]);
    DO_EA(3,2,x32,u3[2]); DO_EB(3,3,x33,u3[3]);
#undef WAITV
#undef DO_EA
#undef DO_EB

    // merge the two accumulator sets (deferred logs: 2 per thread)
    float S = Sa + Sb;
    float L = La + Lb - __logf(prA) - __logf(prB);
    float P = Pa + Pb;
    float Z = Za + Zb;
    float mx; int idx;
    {
        bool take = (mxB > mxA) || (mxB == mxA && idxB < idxA);
        mx  = take ? mxB : mxA;
        idx = take ? idxB : idxA;
    }

    // reduce over the 4 j4-lanes of this pixel within the wave
#pragma unroll
    for (int mask = 16; mask < 64; mask <<= 1){
        S += __shfl_xor(S, mask);
        L += __shfl_xor(L, mask);
        P += __shfl_xor(P, mask);
        Z += __shfl_xor(Z, mask);
        float mo = __shfl_xor(mx, mask);
        int   io = __shfl_xor(idx, mask);
        bool take = (mo > mx) || (mo == mx && io < idx);
        mx  = take ? mo : mx;
        idx = take ? io : idx;
    }
    if (j4 == 0){
        redS[16*v + wl] = S;  redL[16*v + wl] = L;
        redP[16*v + wl] = P;  redZ[16*v + wl] = Z;
        redM[16*v + wl] = mx; redI[16*v + wl] = idx;
    }
    __syncthreads();

    // every thread: full Z for its pixel (16 broadcast LDS reads)
    float Zt = 0.f;
#pragma unroll
    for (int qz = 0; qz < 16; ++qz) Zt += redZ[16*qz + wl];
    const float zinv = fast_rcp(Zt);

    // write normalized f16 sample to Bs as 8B ds_write_b64:
    // n = 256k + 4*nq + m -> chunk c = 32k + (nq>>1), sub byte = 8*(nq&1)+2m
    {
        char* brow = bsb + wl*BS_ROW_B;
        const int sw   = wl & 7;
        const int sub8 = (nq & 1) << 3;
        const int cb2  = nq >> 1;
#pragma unroll
        for (int k = 0; k < 4; ++k){
            f16x4 hv;
            hv[0] = (_Float16)(ev[4*k+0]*zinv);
            hv[1] = (_Float16)(ev[4*k+1]*zinv);
            hv[2] = (_Float16)(ev[4*k+2]*zinv);
            hv[3] = (_Float16)(ev[4*k+3]*zinv);
            *(f16x4*)(brow + (((32*k + cb2) ^ sw) << 4) + sub8) = hv;
        }
    }
    __syncthreads();   // Bs complete

    // ---- GEMM: D[d][pix] = cbT(d,K)*Bs(pix,K); wave v -> d in [16v,16v+16) ----
    // depth-3 a-prefetch (4-buffer ring), pinned (round-5 schedule).
    const _Float16* aBase = cbT + (size_t)(16*v + wl)*32 + j4*8;
    const char* bRow = bsb + wl*BS_ROW_B;
    const int fsw = wl & 7;

    f32x4 acc = (f32x4)0.f;
    f16x8 ar[4];
    ar[0] = *(const f16x8*)(aBase);
    ar[1] = *(const f16x8*)(aBase + 8192);
    ar[2] = *(const f16x8*)(aBase + 2*8192);
    __builtin_amdgcn_sched_barrier(0);

#pragma unroll
    for (int kb = 0; kb < 32; ++kb){
        if (kb + 3 < 32){
            ar[(kb+3)&3] = *(const f16x8*)(aBase + (size_t)(kb+3)*8192);
            __builtin_amdgcn_sched_barrier(0);
        }
        f16x8 bf = *(const f16x8*)(bRow + ((((kb << 2) | j4) ^ fsw) << 4));
        acc = __builtin_amdgcn_mfma_f32_16x16x32_f16(ar[kb&3], bf, acc, 0, 0, 0);
    }

    float* outp = out + (size_t)b*(ND*1024) + h*32 + w0;
#pragma unroll
    for (int r = 0; r < 4; ++r){
        int d = 16*v + 4*j4 + r;
        outp[(size_t)d*1024 + wl] = acc[r];
    }

    // ---- colsum row for this block: thread t sums column t ----
    {
        float s0 = 0.f;
#pragma unroll
        for (int r = 0; r < 16; ++r){
            const char* br = bsb + r*BS_ROW_B;
            const int sw2 = r & 7;
            s0 += (float)*(const _Float16*)(br + ((((t >> 3) ^ sw2) << 4) + 2*(t & 7)));
        }
        colpart[(size_t)blockIdx.x*NN + t] = s0;
    }

    // per-pixel finalize: kl, argmax index (off the barrier critical path)
    if (t < 16){
        float Sq = 0.f, Lq = 0.f, Pq = 0.f, M = -1.f;
        int I = 0x7fffffff;
#pragma unroll
        for (int qz = 0; qz < 16; ++qz){
            Sq += redS[16*qz + t]; Lq += redL[16*qz + t]; Pq += redP[16*qz + t];
            float m = redM[16*qz + t]; int i = redI[16*qz + t];
            bool take = (m > M) || (m == M && i < I);
            M = take ? m : M; I = take ? i : I;
        }
        out[IDX_OFF + row*32 + w0 + t] = (float)I;
        float rS  = fast_rcp(Sq);
        float lnS = __logf(Sq);
        float lgS = (Sq - 0.5f)*lnS - Sq + 0.918938533f + 0.083333333f*rS;
        float dgS = lnS - 0.5f*rS;
        float kl = lgS - Lq - LGAMMA_1024F + (Pq - dgS*(Sq - 1024.f));
#pragma unroll
        for (int mask = 1; mask < 16; mask <<= 1) kl += __shfl_xor(kl, mask);
        if (t == 0) klpart[blockIdx.x] = kl;
    }
}

// ---------------------------------------------------------------------------
// k_redfinal: colsum[n] = sum over 1024 colpart rows (32 blocks x 32 cols,
// atomic-free), then the LAST block to finish computes ppl + kl_loss
// (done-counter + device fences + AGENT loads — R4-proven pattern).
// ---------------------------------------------------------------------------
__global__ __launch_bounds__(256) void k_redfinal(
    const float* __restrict__ colpart, const float* __restrict__ klpart,
    float* __restrict__ colsum, unsigned int* __restrict__ done,
    float* __restrict__ out)
{
    __shared__ float red[8][32];
    __shared__ float red2[8];
    __shared__ int isLast;
    const int nl = threadIdx.x & 31;
    const int rs = threadIdx.x >> 5;             // 0..7
    const int n  = blockIdx.x*32 + nl;
    const float* cp = colpart + (size_t)rs*128*NN + n;
    float s = 0.f;
#pragma unroll 8
    for (int r = 0; r < 128; ++r)
        s += cp[(size_t)r*NN];
    red[rs][nl] = s;
    __syncthreads();
    if (threadIdx.x < 32){
        float tot = 0.f;
#pragma unroll
        for (int i = 0; i < 8; ++i) tot += red[i][threadIdx.x];
        colsum[blockIdx.x*32 + threadIdx.x] = tot;
    }
    __syncthreads();
    if (threadIdx.x == 0){
        __threadfence();                          // release this block's colsum
        unsigned int old = atomicAdd(done, 1u);
        isLast = (old == 31u) ? 1 : 0;
    }
    __syncthreads();
    if (!isLast) return;

    __threadfence();                              // acquire others' colsum
    const int tid = threadIdx.x;
    float sp = 0.f, kls = 0.f;
#pragma unroll
    for (int n2 = tid; n2 < NN; n2 += 256){
        float cv = __hip_atomic_load(&colsum[n2], __ATOMIC_RELAXED,
                                     __HIP_MEMORY_SCOPE_AGENT);
        float avg = cv * (1.f/16384.f);
        sp += avg * logf(avg + 1e-10f);
        kls += klpart[n2];
    }
#pragma unroll
    for (int mask = 1; mask < 64; mask <<= 1){
        sp  += __shfl_xor(sp, mask);
        kls += __shfl_xor(kls, mask);
    }
    if ((tid & 63) == 0){ red2[tid >> 6] = sp; red2[4 + (tid >> 6)] = kls; }
    __syncthreads();
    if (tid == 0){
        float tot = red2[0] + red2[1] + red2[2] + red2[3];
        float klt = red2[4] + red2[5] + red2[6] + red2[7];
        out[PPL_OFF] = expf(-tot);
        out[KL_OFF]  = 1e-3f * (klt * (1.f/16384.f));
    }
}

extern "C" void kernel_launch(void* const* d_in, const int* in_sizes, int n_in,
                              void* d_out, int out_size, void* d_ws, size_t ws_size,
                              hipStream_t stream)
{
    const float* logits = (const float*)d_in[0];
    const float* cb     = (const float*)d_in[1];
    const float* noise  = (const float*)d_in[2];
    float* out = (float*)d_out;

    float* colpart      = (float*)d_ws;                  // 1024*1024 f32 = 4 MB
    float* colsum       = colpart + (size_t)1024*NN;     // 1024
    float* klpart       = colsum + NN;                   // 1024
    unsigned int* done  = (unsigned int*)(klpart + NN);  // 1 (+3 pad)
    _Float16* cbT       = (_Float16*)(klpart + NN + 4);  // 512 KB (16B-aligned)

    k_tr      <<<dim3(32, 4), 256, 0, stream>>>(cb, cbT, done);
    k_mega    <<<dim3(1024), 1024, 0, stream>>>(logits, noise, cbT,
                                                colpart, klpart, out);
    k_redfinal<<<dim3(32),    256, 0, stream>>>(colpart, klpart,
                                                colsum, done, out);
}